// Round 3
// baseline (799.505 us; speedup 1.0000x reference)
//
#include <hip/hip_runtime.h>
#include <stdint.h>

typedef unsigned short u16;
typedef __attribute__((ext_vector_type(8))) short short8;
typedef __attribute__((ext_vector_type(8))) unsigned short ushortx8;
typedef __attribute__((ext_vector_type(4))) float floatx4;

#define DEV __device__ __forceinline__

DEV u16 f2bf(float f) {
  union { float f; unsigned u; } x; x.f = f;
  unsigned u = x.u + 0x7fffu + ((x.u >> 16) & 1u);
  return (u16)(u >> 16);
}
DEV float bf2f(u16 h) {
  union { unsigned u; float f; } x; x.u = ((unsigned)h) << 16;
  return x.f;
}
DEV float scrub(float x) {  // clamp + NaN-scrub (IEEE min/max drop NaN operand)
  return fminf(fmaxf(x, -65504.0f), 65504.0f);
}

// ---------------------------------------------------------------------------
// Projection GEMM: C[M,N] = A[M,K] * W[N,K]^T.  A,W fp32; C bf16 head-split.
// M=8192, N=K=1024. 128x128 tile, BK=64, 256 threads, 4 waves (64x64 each).
// LDS tiles pitch 72 (144 B = 16-aligned), fp32->bf16 convert during staging.
// ---------------------------------------------------------------------------
__global__ __launch_bounds__(256, 2) void proj_gemm(
    const float* __restrict__ Aq, const float* __restrict__ Ak, const float* __restrict__ Av,
    const float* __restrict__ Wq, const float* __restrict__ Wk, const float* __restrict__ Wv,
    u16* __restrict__ Oq, u16* __restrict__ Ok, u16* __restrict__ Ov)
{
  constexpr int K = 1024;
  const int z = blockIdx.z;
  const float* A = z == 0 ? Aq : (z == 1 ? Ak : Av);
  const float* W = z == 0 ? Wq : (z == 1 ? Wk : Wv);
  u16* Out = z == 0 ? Oq : (z == 1 ? Ok : Ov);

  const int tid = threadIdx.x;
  const int w = tid >> 6, lane = tid & 63;
  const int quad = lane >> 4, l16 = lane & 15;
  const int m0 = blockIdx.y * 128, n0 = blockIdx.x * 128;
  const int wm = (w & 1) * 64, wn = (w >> 1) * 64;

  __shared__ u16 As[128 * 72];
  __shared__ u16 Bs[128 * 72];

  floatx4 acc[4][4];
#pragma unroll
  for (int i = 0; i < 4; ++i)
#pragma unroll
    for (int j = 0; j < 4; ++j) acc[i][j] = (floatx4)0.0f;

  for (int k0 = 0; k0 < K; k0 += 64) {
    // stage A and W 128x64 fp32 tiles -> bf16 LDS (2048 float4 chunks each)
#pragma unroll
    for (int i = 0; i < 8; ++i) {
      int lin = i * 256 + tid;
      int row = lin >> 4, c4 = (lin & 15) * 4;
      float4 a = *(const float4*)&A[(size_t)(m0 + row) * K + k0 + c4];
      u16* d = &As[row * 72 + c4];
      d[0] = f2bf(a.x); d[1] = f2bf(a.y); d[2] = f2bf(a.z); d[3] = f2bf(a.w);
    }
#pragma unroll
    for (int i = 0; i < 8; ++i) {
      int lin = i * 256 + tid;
      int row = lin >> 4, c4 = (lin & 15) * 4;
      float4 b = *(const float4*)&W[(size_t)(n0 + row) * K + k0 + c4];
      u16* d = &Bs[row * 72 + c4];
      d[0] = f2bf(b.x); d[1] = f2bf(b.y); d[2] = f2bf(b.z); d[3] = f2bf(b.w);
    }
    __syncthreads();

#pragma unroll
    for (int kk = 0; kk < 2; ++kk) {
      short8 af[4], bf[4];
#pragma unroll
      for (int mi = 0; mi < 4; ++mi)
        af[mi] = *(const short8*)&As[(wm + mi * 16 + l16) * 72 + kk * 32 + quad * 8];
#pragma unroll
      for (int ni = 0; ni < 4; ++ni)
        bf[ni] = *(const short8*)&Bs[(wn + ni * 16 + l16) * 72 + kk * 32 + quad * 8];
#pragma unroll
      for (int mi = 0; mi < 4; ++mi)
#pragma unroll
        for (int ni = 0; ni < 4; ++ni)
          acc[mi][ni] = __builtin_amdgcn_mfma_f32_16x16x32_bf16(af[mi], bf[ni], acc[mi][ni], 0, 0, 0);
    }
    __syncthreads();
  }

  // C/D layout: col=lane&15, row=quad*4+reg.  Store bf16 head-split (B,H,L,DK).
#pragma unroll
  for (int mi = 0; mi < 4; ++mi) {
#pragma unroll
    for (int ni = 0; ni < 4; ++ni) {
      int rr = m0 + wm + mi * 16 + quad * 4;
      int cc = n0 + wn + ni * 16 + l16;
#pragma unroll
      for (int reg = 0; reg < 4; ++reg) {
        int row = rr + reg;
        int bb = row >> 11, ll = row & 2047;   // L=2048
        int hh = cc >> 6, dk = cc & 63;        // DK=64
        Out[(((size_t)bb * 16 + hh) * 2048 + ll) * 64 + dk] = f2bf(scrub(acc[mi][ni][reg]));
      }
    }
  }
}

// ---------------------------------------------------------------------------
// Output GEMM: C[M,N] = A[M,K] * W[N,K]^T.  A bf16 head-split, W fp32,
// C fp32 row-major (the final output).
// ---------------------------------------------------------------------------
__global__ __launch_bounds__(256, 2) void out_gemm(
    const u16* __restrict__ Ah, const float* __restrict__ Wo, float* __restrict__ Out)
{
  constexpr int K = 1024;
  const int tid = threadIdx.x;
  const int w = tid >> 6, lane = tid & 63;
  const int quad = lane >> 4, l16 = lane & 15;
  const int m0 = blockIdx.y * 128, n0 = blockIdx.x * 128;
  const int wm = (w & 1) * 64, wn = (w >> 1) * 64;

  __shared__ u16 As[128 * 72];
  __shared__ u16 Bs[128 * 72];

  floatx4 acc[4][4];
#pragma unroll
  for (int i = 0; i < 4; ++i)
#pragma unroll
    for (int j = 0; j < 4; ++j) acc[i][j] = (floatx4)0.0f;

  for (int k0 = 0; k0 < K; k0 += 64) {
    int hh = k0 >> 6;  // head index; one head per 64-wide K step
#pragma unroll
    for (int i = 0; i < 4; ++i) {
      int lin = i * 256 + tid;               // 1024 chunks of 8 u16 (16B)
      int row = lin >> 3, s = lin & 7;
      int gr = m0 + row;
      int bb = gr >> 11, tok = gr & 2047;
      ushortx8 v8 = *(const ushortx8*)&Ah[(((size_t)bb * 16 + hh) * 2048 + tok) * 64 + s * 8];
      *(ushortx8*)&As[row * 72 + s * 8] = v8;
    }
#pragma unroll
    for (int i = 0; i < 8; ++i) {
      int lin = i * 256 + tid;
      int row = lin >> 4, c4 = (lin & 15) * 4;
      float4 b = *(const float4*)&Wo[(size_t)(n0 + row) * K + k0 + c4];
      u16* d = &Bs[row * 72 + c4];
      d[0] = f2bf(b.x); d[1] = f2bf(b.y); d[2] = f2bf(b.z); d[3] = f2bf(b.w);
    }
    __syncthreads();

#pragma unroll
    for (int kk = 0; kk < 2; ++kk) {
      short8 af[4], bf[4];
#pragma unroll
      for (int mi = 0; mi < 4; ++mi)
        af[mi] = *(const short8*)&As[(wm + mi * 16 + l16) * 72 + kk * 32 + quad * 8];
#pragma unroll
      for (int ni = 0; ni < 4; ++ni)
        bf[ni] = *(const short8*)&Bs[(wn + ni * 16 + l16) * 72 + kk * 32 + quad * 8];
#pragma unroll
      for (int mi = 0; mi < 4; ++mi)
#pragma unroll
        for (int ni = 0; ni < 4; ++ni)
          acc[mi][ni] = __builtin_amdgcn_mfma_f32_16x16x32_bf16(af[mi], bf[ni], acc[mi][ni], 0, 0, 0);
    }
    __syncthreads();
  }

#pragma unroll
  for (int mi = 0; mi < 4; ++mi) {
#pragma unroll
    for (int ni = 0; ni < 4; ++ni) {
      int rr = m0 + wm + mi * 16 + quad * 4;
      int cc = n0 + wn + ni * 16 + l16;
#pragma unroll
      for (int reg = 0; reg < 4; ++reg)
        Out[(size_t)(rr + reg) * 1024 + cc] = scrub(acc[mi][ni][reg]);
    }
  }
}

// ---------------------------------------------------------------------------
// Flash attention: grid (L/128, H, B), 256 threads. Wave w owns Q rows
// [w*32, w*32+32). All tensors bf16 head-split (B,H,L,DK). Output written
// over the same head-split Q rows this block staged (block-private).
// ---------------------------------------------------------------------------
__global__ __launch_bounds__(256, 2) void attn_kernel(
    const u16* Qh, const u16* __restrict__ Kh,
    const u16* __restrict__ Vh, u16* O)
{
  constexpr int L = 2048, DK = 64, H = 16;
  constexpr float SC2 = 0.125f * 1.44269504088896f;  // SCALE * log2(e)

  const int tid = threadIdx.x;
  const int w = tid >> 6, lane = tid & 63;
  const int quad = lane >> 4, l16 = lane & 15;
  const int q0 = blockIdx.x * 128, h = blockIdx.y, b = blockIdx.z;
  const int bh = b * H + h;

  __shared__ u16 QP[128 * 72];  // Q staging, then 4x per-wave P tiles (32x72)
  __shared__ u16 Ks[64 * 72];
  __shared__ u16 Vt[64 * 72];

  const u16* Qg = Qh + ((size_t)bh * L + q0) * DK;
  const u16* Kb = Kh + (size_t)bh * L * DK;
  const u16* Vb = Vh + (size_t)bh * L * DK;

#pragma unroll
  for (int i = 0; i < 4; ++i) {
    int lin = i * 256 + tid;
    int r = lin >> 3, c8 = (lin & 7) * 8;
    *(uint4*)&QP[r * 72 + c8] = *(const uint4*)&Qg[lin * 8];
  }
  __syncthreads();

  short8 qf[2][2];
#pragma unroll
  for (int mi = 0; mi < 2; ++mi)
#pragma unroll
    for (int kk = 0; kk < 2; ++kk)
      qf[mi][kk] = *(const short8*)&QP[(w * 32 + mi * 16 + l16) * 72 + kk * 32 + quad * 8];

  floatx4 o[2][4];
  float m_i[2][4], l_i[2][4];
#pragma unroll
  for (int mi = 0; mi < 2; ++mi) {
#pragma unroll
    for (int nt = 0; nt < 4; ++nt) o[mi][nt] = (floatx4)0.0f;
#pragma unroll
    for (int r = 0; r < 4; ++r) { m_i[mi][r] = -1e30f; l_i[mi][r] = 0.0f; }
  }

  u16* Pl = &QP[w * 32 * 72];

  for (int j0 = 0; j0 < L; j0 += 64) {
    __syncthreads();
    const u16* Kg = Kb + (size_t)j0 * DK;
    const u16* Vg = Vb + (size_t)j0 * DK;
#pragma unroll
    for (int i = 0; i < 2; ++i) {
      int lin = i * 256 + tid;
      int r = lin >> 3, c8 = (lin & 7) * 8;
      *(uint4*)&Ks[r * 72 + c8] = *(const uint4*)&Kg[lin * 8];
    }
#pragma unroll
    for (int i = 0; i < 2; ++i) {
      int lin = i * 256 + tid;
      int r = lin >> 3, c8 = (lin & 7) * 8;
      ushortx8 vv = *(const ushortx8*)&Vg[lin * 8];
#pragma unroll
      for (int j = 0; j < 8; ++j) Vt[(c8 + j) * 72 + r] = vv[j];
    }
    __syncthreads();

    short8 kf[4][2];
#pragma unroll
    for (int nt = 0; nt < 4; ++nt)
#pragma unroll
      for (int kk = 0; kk < 2; ++kk)
        kf[nt][kk] = *(const short8*)&Ks[(nt * 16 + l16) * 72 + kk * 32 + quad * 8];

    floatx4 s[2][4];
#pragma unroll
    for (int mi = 0; mi < 2; ++mi)
#pragma unroll
      for (int nt = 0; nt < 4; ++nt) {
        s[mi][nt] = (floatx4)0.0f;
#pragma unroll
        for (int kk = 0; kk < 2; ++kk)
          s[mi][nt] = __builtin_amdgcn_mfma_f32_16x16x32_bf16(qf[mi][kk], kf[nt][kk], s[mi][nt], 0, 0, 0);
      }

#pragma unroll
    for (int mi = 0; mi < 2; ++mi) {
#pragma unroll
      for (int nt = 0; nt < 4; ++nt) s[mi][nt] *= SC2;
      float mx[4], al[4], rs[4];
#pragma unroll
      for (int r = 0; r < 4; ++r)
        mx[r] = fmaxf(fmaxf(s[mi][0][r], s[mi][1][r]), fmaxf(s[mi][2][r], s[mi][3][r]));
#pragma unroll
      for (int off = 1; off < 16; off <<= 1)
#pragma unroll
        for (int r = 0; r < 4; ++r)
          mx[r] = fmaxf(mx[r], __shfl_xor(mx[r], off, 16));
#pragma unroll
      for (int r = 0; r < 4; ++r) {
        float mnew = fmaxf(m_i[mi][r], mx[r]);
        al[r] = exp2f(fminf(m_i[mi][r] - mnew, 0.0f));
        m_i[mi][r] = mnew;
        float acc = 0.0f;
#pragma unroll
        for (int nt = 0; nt < 4; ++nt) {
          float p = exp2f(fminf(s[mi][nt][r] - mnew, 0.0f));
          u16 pb = f2bf(p);
          Pl[(mi * 16 + quad * 4 + r) * 72 + nt * 16 + l16] = pb;
          acc += bf2f(pb);
        }
        rs[r] = acc;
      }
#pragma unroll
      for (int off = 1; off < 16; off <<= 1)
#pragma unroll
        for (int r = 0; r < 4; ++r)
          rs[r] += __shfl_xor(rs[r], off, 16);
#pragma unroll
      for (int r = 0; r < 4; ++r) {
        l_i[mi][r] = l_i[mi][r] * al[r] + rs[r];
#pragma unroll
        for (int nt = 0; nt < 4; ++nt) o[mi][nt][r] *= al[r];   // per-row rescale
      }
    }

    asm volatile("s_waitcnt lgkmcnt(0)" ::: "memory");

    short8 pf[2][2], vf[4][2];
#pragma unroll
    for (int mi = 0; mi < 2; ++mi)
#pragma unroll
      for (int kk = 0; kk < 2; ++kk)
        pf[mi][kk] = *(const short8*)&Pl[(mi * 16 + l16) * 72 + kk * 32 + quad * 8];
#pragma unroll
    for (int nt = 0; nt < 4; ++nt)
#pragma unroll
      for (int kk = 0; kk < 2; ++kk)
        vf[nt][kk] = *(const short8*)&Vt[(nt * 16 + l16) * 72 + kk * 32 + quad * 8];
#pragma unroll
    for (int mi = 0; mi < 2; ++mi)
#pragma unroll
      for (int nt = 0; nt < 4; ++nt)
#pragma unroll
        for (int kk = 0; kk < 2; ++kk)
          o[mi][nt] = __builtin_amdgcn_mfma_f32_16x16x32_bf16(pf[mi][kk], vf[nt][kk], o[mi][nt], 0, 0, 0);
  }

  // epilogue: write O over this block's own head-split Q rows (bf16)
#pragma unroll
  for (int mi = 0; mi < 2; ++mi) {
    float inv[4];
#pragma unroll
    for (int r = 0; r < 4; ++r) inv[r] = 1.0f / fmaxf(l_i[mi][r], 1e-30f);
#pragma unroll
    for (int nt = 0; nt < 4; ++nt)
#pragma unroll
      for (int r = 0; r < 4; ++r) {
        int token = q0 + w * 32 + mi * 16 + quad * 4 + r;
        O[((size_t)bh * L + token) * 64 + nt * 16 + l16] =
            f2bf(scrub(o[mi][nt][r] * inv[r]));
      }
  }
}

// ---------------------------------------------------------------------------
extern "C" void kernel_launch(void* const* d_in, const int* in_sizes, int n_in,
                              void* d_out, int out_size, void* d_ws, size_t ws_size,
                              hipStream_t stream) {
  const float* q  = (const float*)d_in[0];
  const float* k  = (const float*)d_in[1];
  const float* v  = (const float*)d_in[2];
  const float* wq = (const float*)d_in[3];
  const float* wk = (const float*)d_in[4];
  const float* wv = (const float*)d_in[5];
  const float* wo = (const float*)d_in[6];
  float* out = (float*)d_out;

  const size_t NE = (size_t)4 * 16 * 2048 * 64;  // 8388608 elems
  // bf16 scratch: Q in ws (16 MiB); K,V in d_out's 32 MiB (fp32 buffer),
  // both dead before the final fp32 overwrite (stream-ordered).
  u16* Qw = (u16*)d_ws;
  u16* Kw = (u16*)d_out;
  u16* Vw = Kw + NE;

  // QKV projections: fp32 in -> bf16 head-split (B,H,L,DK)
  dim3 g1(8, 64, 3);
  proj_gemm<<<g1, dim3(256), 0, stream>>>(q, k, v, wq, wk, wv, Qw, Kw, Vw);

  // flash attention; output overwrites Qw (head-split, block-private rows)
  dim3 g2(16, 16, 4);
  attn_kernel<<<g2, dim3(256), 0, stream>>>(Qw, Kw, Vw, Qw);

  // output projection: head-split bf16 A -> fp32 row-major d_out
  dim3 g3(8, 64, 1);
  out_gemm<<<g3, dim3(256), 0, stream>>>(Qw, wo, out);
}